// Round 1
// baseline (459.209 us; speedup 1.0000x reference)
//
#include <hip/hip_runtime.h>

#define NB 128
#define NN 50000
#define NE 300000
#define ND 256
#define NP 8

typedef __attribute__((ext_vector_type(4))) float f32x4;
typedef __attribute__((ext_vector_type(8))) short s16x8;

__device__ __forceinline__ unsigned short bf16rtn(float f) {
    unsigned int u = __float_as_uint(f);
    unsigned int r = (u + 0x7fffu + ((u >> 16) & 1u)) >> 16;
    return (unsigned short)r;
}

// swizzled LDS byte offset for [row][256 bf16] tiles (row stride 512B),
// XOR bits 4-6 with row&7 -> conflict-free ds_read_b128 (guide G4 pattern)
__device__ __forceinline__ int swz(int row, int kbyte) {
    return row * 512 + (kbyte ^ ((row & 7) << 4));
}

__device__ __forceinline__ s16x8 pack8(f32x4 a, f32x4 b) {
    s16x8 v;
    v[0] = (short)bf16rtn(a[0]); v[1] = (short)bf16rtn(a[1]);
    v[2] = (short)bf16rtn(a[2]); v[3] = (short)bf16rtn(a[3]);
    v[4] = (short)bf16rtn(b[0]); v[5] = (short)bf16rtn(b[1]);
    v[6] = (short)bf16rtn(b[2]); v[7] = (short)bf16rtn(b[3]);
    return v;
}

__device__ __forceinline__ float eluf(float x) {
    return x > 0.f ? x : __expf(x) - 1.f;
}

// ---------------- segment boundary kernel (node_indices is sorted) ---------
__global__ void k_starts(const int* __restrict__ idx, int* __restrict__ starts) {
    int n = blockIdx.x * blockDim.x + threadIdx.x;
    if (n >= NN) return;
    int cur = idx[n];
    int prev = (n == 0) ? -1 : idx[n - 1];
    for (int b2 = prev + 1; b2 <= cur; ++b2) starts[b2] = n;
    if (n == NN - 1)
        for (int b2 = cur + 1; b2 <= NB; ++b2) starts[b2] = NN;
}

// ---------------- W_edge f32 -> bf16 --------------------------------------
__global__ void k_wedge_bf16(const float* __restrict__ w, unsigned short* __restrict__ o) {
    int i = (blockIdx.x * 256 + threadIdx.x) * 4;
    f32x4 v = *(const f32x4*)(w + i);
    o[i + 0] = bf16rtn(v[0]); o[i + 1] = bf16rtn(v[1]);
    o[i + 2] = bf16rtn(v[2]); o[i + 3] = bf16rtn(v[3]);
}

// ---------------- node kernel ---------------------------------------------
// grid = 512: block (b = idx&127, c = idx>>7) handles graph b, cols 64c..64c+64.
// LDS: W_eff slice [64 cols][256 k] bf16 (32KB, staged once, combined from 8 W_p)
//      + A tile [64 nodes][256 k] bf16 (32KB, per M-tile)
__global__ __launch_bounds__(256) void k_nodes(
    const float* __restrict__ instr, const float* __restrict__ sim,
    const float* __restrict__ attrs, const float* __restrict__ Wp,
    const float* __restrict__ wns, const int* __restrict__ starts,
    float* __restrict__ state_logits)
{
    extern __shared__ char lds[];
    char* Wl = lds;            // 32768 B
    char* Al = lds + 32768;    // 32768 B

    int b = blockIdx.x & 127;
    int c = blockIdx.x >> 7;
    int col0 = c * 64;
    int tid = threadIdx.x;
    int lane = tid & 63;
    int wave = tid >> 6;

    // ---- stage W_eff slice: cols [col0, col0+64), all 256 k ----
    {
        float s_[NP];
#pragma unroll
        for (int p = 0; p < NP; ++p) s_[p] = sim[b * NP + p];
        int cl = tid >> 2;          // 0..63 local col
        int k0 = (tid & 3) * 64;    // k chunk base
        const float* wbase = Wp + (size_t)(col0 + cl) * ND + k0;
#pragma unroll
        for (int j = 0; j < 8; ++j) {
            float g[8] = {0.f, 0.f, 0.f, 0.f, 0.f, 0.f, 0.f, 0.f};
#pragma unroll
            for (int p = 0; p < NP; ++p) {
                const float* wp = wbase + (size_t)p * ND * ND + j * 8;
                f32x4 w0 = *(const f32x4*)(wp);
                f32x4 w1 = *(const f32x4*)(wp + 4);
                g[0] += s_[p] * w0[0]; g[1] += s_[p] * w0[1];
                g[2] += s_[p] * w0[2]; g[3] += s_[p] * w0[3];
                g[4] += s_[p] * w1[0]; g[5] += s_[p] * w1[1];
                g[6] += s_[p] * w1[2]; g[7] += s_[p] * w1[3];
            }
            s16x8 v;
            v[0] = (short)bf16rtn(g[0]); v[1] = (short)bf16rtn(g[1]);
            v[2] = (short)bf16rtn(g[2]); v[3] = (short)bf16rtn(g[3]);
            v[4] = (short)bf16rtn(g[4]); v[5] = (short)bf16rtn(g[5]);
            v[6] = (short)bf16rtn(g[6]); v[7] = (short)bf16rtn(g[7]);
            *(s16x8*)(Wl + swz(cl, (k0 + j * 8) * 2)) = v;
        }
    }

    // epilogue constants: instr[b][col], w_node_score[col] for this lane's cols
    float iv[4], wv[4];
#pragma unroll
    for (int cg = 0; cg < 4; ++cg) {
        int col = col0 + cg * 16 + (lane & 15);
        iv[cg] = instr[b * ND + col];
        wv[cg] = wns[col];
    }

    int s0 = starts[b], s1 = starts[b + 1];

    for (int node0 = s0; node0 < s1; node0 += 64) {
        __syncthreads();
        // ---- stage A tile: nodes node0..node0+64, all k, f32 -> bf16 ----
        {
            int r = tid >> 2;
            int k0 = (tid & 3) * 64;
            int node = node0 + r;
            bool valid = node < s1;
            const float* abase = attrs + (size_t)node * ND + k0;
#pragma unroll
            for (int j = 0; j < 8; ++j) {
                f32x4 a0 = {0.f, 0.f, 0.f, 0.f}, a1 = {0.f, 0.f, 0.f, 0.f};
                if (valid) {
                    a0 = *(const f32x4*)(abase + j * 8);
                    a1 = *(const f32x4*)(abase + j * 8 + 4);
                }
                *(s16x8*)(Al + swz(r, (k0 + j * 8) * 2)) = pack8(a0, a1);
            }
        }
        __syncthreads();

        // ---- MFMA: wave handles rows 16w..16w+16 of tile, 64 cols ----
        f32x4 acc[4] = {};
        int arow = 16 * wave + (lane & 15);
        int kg = 8 * (lane >> 4);
#pragma unroll
        for (int kk = 0; kk < 8; ++kk) {
            int kbyte = (kk * 32 + kg) * 2;
            s16x8 a = *(const s16x8*)(Al + swz(arow, kbyte));
#pragma unroll
            for (int cg = 0; cg < 4; ++cg) {
                s16x8 bf = *(const s16x8*)(Wl + swz(cg * 16 + (lane & 15), kbyte));
                acc[cg] = __builtin_amdgcn_mfma_f32_16x16x32_bf16(a, bf, acc[cg], 0, 0, 0);
            }
        }

        // ---- epilogue: logit partial = sum_d w_ns[d]*elu(instr[d]*y[d]) ----
#pragma unroll
        for (int reg = 0; reg < 4; ++reg) {
            int rl = 16 * wave + 4 * (lane >> 4) + reg;  // row in tile
            float p = 0.f;
#pragma unroll
            for (int cg = 0; cg < 4; ++cg) {
                float x = iv[cg] * acc[cg][reg];
                p += wv[cg] * eluf(x);
            }
            p += __shfl_xor(p, 1, 64);
            p += __shfl_xor(p, 2, 64);
            p += __shfl_xor(p, 4, 64);
            p += __shfl_xor(p, 8, 64);
            int node = node0 + rl;
            if ((lane & 15) == 0 && node < s1)
                atomicAdd(&state_logits[node], p);
        }
    }
}

// ---------------- edge kernel ---------------------------------------------
// grid = ceil(E/64): block handles 64 edges x all 256 cols.
// A tile in swizzled LDS; B frags (bf16 W_edge) straight from global/L2.
__global__ __launch_bounds__(256) void k_edges(
    const float* __restrict__ instr, const float* __restrict__ dist,
    const float* __restrict__ eattrs, const unsigned short* __restrict__ Wbf,
    const float* __restrict__ wrs, const int* __restrict__ ebidx,
    const int* __restrict__ eidx, float* __restrict__ rel_logits)
{
    extern __shared__ char lds[];
    char* Al = lds;                          // 32768 B
    int* ebs = (int*)(lds + 32768);          // 64
    int* dsts = ebs + 64;                    // 64
    float* dscs = (float*)(dsts + 64);       // 64

    int e0 = blockIdx.x * 64;
    int tid = threadIdx.x;
    int lane = tid & 63;
    int wave = tid >> 6;

    if (tid < 64) {
        int e = e0 + tid;
        if (e < NE) {
            ebs[tid] = ebidx[e];
            int src = eidx[e];
            dsts[tid] = eidx[NE + e];
            dscs[tid] = dist[src];
        } else {
            ebs[tid] = 0; dsts[tid] = 0; dscs[tid] = 0.f;
        }
    }
    // ---- stage A tile (edge_attrs f32 -> bf16) ----
    {
        int r = tid >> 2;
        int k0 = (tid & 3) * 64;
        int e = e0 + r;
        bool valid = e < NE;
        const float* abase = eattrs + (size_t)e * ND + k0;
#pragma unroll
        for (int j = 0; j < 8; ++j) {
            f32x4 a0 = {0.f, 0.f, 0.f, 0.f}, a1 = {0.f, 0.f, 0.f, 0.f};
            if (valid) {
                a0 = *(const f32x4*)(abase + j * 8);
                a1 = *(const f32x4*)(abase + j * 8 + 4);
            }
            *(s16x8*)(Al + swz(r, (k0 + j * 8) * 2)) = pack8(a0, a1);
        }
    }
    __syncthreads();

    float wrelv[16];
#pragma unroll
    for (int cg = 0; cg < 16; ++cg) wrelv[cg] = wrs[cg * 16 + (lane & 15)];

    f32x4 acc[16] = {};
    int arow = 16 * wave + (lane & 15);
    int kg = 8 * (lane >> 4);
#pragma unroll
    for (int kk = 0; kk < 8; ++kk) {
        int kbyte = (kk * 32 + kg) * 2;
        s16x8 a = *(const s16x8*)(Al + swz(arow, kbyte));
#pragma unroll
        for (int cg = 0; cg < 16; ++cg) {
            const unsigned short* wp = Wbf + (size_t)(cg * 16 + (lane & 15)) * ND + kk * 32 + kg;
            s16x8 bf = *(const s16x8*)wp;
            acc[cg] = __builtin_amdgcn_mfma_f32_16x16x32_bf16(a, bf, acc[cg], 0, 0, 0);
        }
    }

    // epilogue: per edge e, c = dist[src]*sum_d w_rel[d]*elu(instr[b_e,d]*y[d])
#pragma unroll
    for (int reg = 0; reg < 4; ++reg) {
        int rl = 16 * wave + 4 * (lane >> 4) + reg;
        const float* irow = instr + (size_t)ebs[rl] * ND;
        float p = 0.f;
#pragma unroll
        for (int cg = 0; cg < 16; ++cg) {
            float x = irow[cg * 16 + (lane & 15)] * acc[cg][reg];
            p += wrelv[cg] * eluf(x);
        }
        p += __shfl_xor(p, 1, 64);
        p += __shfl_xor(p, 2, 64);
        p += __shfl_xor(p, 4, 64);
        p += __shfl_xor(p, 8, 64);
        if ((lane & 15) == 0 && e0 + rl < NE)
            atomicAdd(&rel_logits[dsts[rl]], dscs[rl] * p);
    }
}

// ---------------- per-graph softmaxes + final mix -------------------------
__global__ __launch_bounds__(256) void k_softmax_mix(
    const float* __restrict__ state_l, const float* __restrict__ rel_l,
    const int* __restrict__ starts, const float* __restrict__ relsim,
    float* __restrict__ out)
{
    __shared__ float wms[4], wmr[4], wss[4], wsr[4];
    int b = blockIdx.x;
    int s0 = starts[b], s1 = starts[b + 1];
    if (s1 <= s0) return;
    int tid = threadIdx.x, lane = tid & 63, wave = tid >> 6;

    float ms = -3.4e38f, mr = -3.4e38f;
    for (int n = s0 + tid; n < s1; n += 256) {
        ms = fmaxf(ms, state_l[n]);
        mr = fmaxf(mr, rel_l[n]);
    }
#pragma unroll
    for (int m = 1; m < 64; m <<= 1) {
        ms = fmaxf(ms, __shfl_xor(ms, m, 64));
        mr = fmaxf(mr, __shfl_xor(mr, m, 64));
    }
    if (lane == 0) { wms[wave] = ms; wmr[wave] = mr; }
    __syncthreads();
    ms = fmaxf(fmaxf(wms[0], wms[1]), fmaxf(wms[2], wms[3]));
    mr = fmaxf(fmaxf(wmr[0], wmr[1]), fmaxf(wmr[2], wmr[3]));

    float ss = 0.f, sr = 0.f;
    for (int n = s0 + tid; n < s1; n += 256) {
        ss += __expf(state_l[n] - ms);
        sr += __expf(rel_l[n] - mr);
    }
#pragma unroll
    for (int m = 1; m < 64; m <<= 1) {
        ss += __shfl_xor(ss, m, 64);
        sr += __shfl_xor(sr, m, 64);
    }
    if (lane == 0) { wss[wave] = ss; wsr[wave] = sr; }
    __syncthreads();
    ss = wss[0] + wss[1] + wss[2] + wss[3];
    sr = wsr[0] + wsr[1] + wsr[2] + wsr[3];

    float rb = relsim[b];
    float iss = 1.f / ss, isr = 1.f / sr;
    for (int n = s0 + tid; n < s1; n += 256) {
        out[n] = rb * __expf(rel_l[n] - mr) * isr
               + (1.f - rb) * __expf(state_l[n] - ms) * iss;
    }
}

extern "C" void kernel_launch(void* const* d_in, const int* in_sizes, int n_in,
                              void* d_out, int out_size, void* d_ws, size_t ws_size,
                              hipStream_t stream) {
    const float* instr  = (const float*)d_in[0];
    const float* dist   = (const float*)d_in[1];
    const float* sim    = (const float*)d_in[2];
    const float* relsim = (const float*)d_in[3];
    const float* nattr  = (const float*)d_in[4];
    const float* eattr  = (const float*)d_in[5];
    const float* Wp     = (const float*)d_in[6];
    const float* We     = (const float*)d_in[7];
    const float* wns    = (const float*)d_in[8];
    const float* wrs    = (const float*)d_in[9];
    const int* nidx     = (const int*)d_in[10];
    const int* ebidx    = (const int*)d_in[11];
    const int* eidx     = (const int*)d_in[12];
    float* out = (float*)d_out;

    char* ws = (char*)d_ws;
    float* rel_logits   = (float*)ws;            // N floats
    float* state_logits = rel_logits + NN;       // N floats
    int* starts         = (int*)(ws + 400128);   // B+1 ints
    unsigned short* Wbf = (unsigned short*)(ws + 400768); // 256*256 bf16

    hipMemsetAsync(rel_logits, 0, 2 * NN * sizeof(float), stream);
    k_wedge_bf16<<<64, 256, 0, stream>>>(We, Wbf);
    k_starts<<<(NN + 255) / 256, 256, 0, stream>>>(nidx, starts);
    k_edges<<<(NE + 63) / 64, 256, 33536, stream>>>(instr, dist, eattr, Wbf, wrs,
                                                    ebidx, eidx, rel_logits);
    k_nodes<<<512, 256, 65536, stream>>>(instr, sim, nattr, Wp, wns, starts,
                                         state_logits);
    k_softmax_mix<<<NB, 256, 0, stream>>>(state_logits, rel_logits, starts,
                                          relsim, out);
}

// Round 2
// 387.021 us; speedup vs baseline: 1.1865x; 1.1865x over previous
//
#include <hip/hip_runtime.h>

#define NB 128
#define NN 50000
#define NE 300000
#define ND 256
#define NP 8
#define KQ 8   // node-kernel tile-stride blocks per graph

typedef __attribute__((ext_vector_type(4))) float f32x4;
typedef __attribute__((ext_vector_type(8))) short s16x8;

__device__ __forceinline__ unsigned short bf16rtn(float f) {
    unsigned int u = __float_as_uint(f);
    unsigned int r = (u + 0x7fffu + ((u >> 16) & 1u)) >> 16;
    return (unsigned short)r;
}

// swizzled LDS byte offset for [row][256 bf16] tiles (row stride 512B),
// XOR bits 4-6 with row&7 -> conflict-free ds_read_b128 (guide G4 pattern)
__device__ __forceinline__ int swz(int row, int kbyte) {
    return row * 512 + (kbyte ^ ((row & 7) << 4));
}

__device__ __forceinline__ s16x8 pack8(f32x4 a, f32x4 b) {
    s16x8 v;
    v[0] = (short)bf16rtn(a[0]); v[1] = (short)bf16rtn(a[1]);
    v[2] = (short)bf16rtn(a[2]); v[3] = (short)bf16rtn(a[3]);
    v[4] = (short)bf16rtn(b[0]); v[5] = (short)bf16rtn(b[1]);
    v[6] = (short)bf16rtn(b[2]); v[7] = (short)bf16rtn(b[3]);
    return v;
}

__device__ __forceinline__ float eluf(float x) {
    return x > 0.f ? x : __expf(x) - 1.f;
}

// ---------------- segment boundary kernel (node_indices is sorted) ---------
__global__ void k_starts(const int* __restrict__ idx, int* __restrict__ starts) {
    int n = blockIdx.x * blockDim.x + threadIdx.x;
    if (n >= NN) return;
    int cur = idx[n];
    int prev = (n == 0) ? -1 : idx[n - 1];
    for (int b2 = prev + 1; b2 <= cur; ++b2) starts[b2] = n;
    if (n == NN - 1)
        for (int b2 = cur + 1; b2 <= NB; ++b2) starts[b2] = NN;
}

// ---------------- W_edge f32 -> bf16 --------------------------------------
__global__ void k_wedge_bf16(const float* __restrict__ w, unsigned short* __restrict__ o) {
    int i = (blockIdx.x * 256 + threadIdx.x) * 4;
    f32x4 v = *(const f32x4*)(w + i);
    o[i + 0] = bf16rtn(v[0]); o[i + 1] = bf16rtn(v[1]);
    o[i + 2] = bf16rtn(v[2]); o[i + 3] = bf16rtn(v[3]);
}

// ---------------- W_eff[b] = sum_p sim[b,p] * W_p  (f32 -> bf16) ----------
// grid (32, 8): x = 8-elem-chunk block (256 thr * 8 elems = 2048 elems),
// y = 16-graph octet. Wp slice held in regs; loop over graphs.
__global__ __launch_bounds__(256) void k_weff(
    const float* __restrict__ sim, const float* __restrict__ Wp,
    unsigned short* __restrict__ Weff)
{
    int chunk = blockIdx.x * 256 + threadIdx.x;   // 0..8191, 8 elems each
    int off = chunk * 8;                           // offset into [D*D]
    float wp[NP][8];
#pragma unroll
    for (int p = 0; p < NP; ++p) {
        const float* src = Wp + (size_t)p * ND * ND + off;
        f32x4 w0 = *(const f32x4*)src;
        f32x4 w1 = *(const f32x4*)(src + 4);
        wp[p][0] = w0[0]; wp[p][1] = w0[1]; wp[p][2] = w0[2]; wp[p][3] = w0[3];
        wp[p][4] = w1[0]; wp[p][5] = w1[1]; wp[p][6] = w1[2]; wp[p][7] = w1[3];
    }
    int b0 = blockIdx.y * 16;
    for (int bb = 0; bb < 16; ++bb) {
        int b = b0 + bb;
        float g[8] = {0.f, 0.f, 0.f, 0.f, 0.f, 0.f, 0.f, 0.f};
#pragma unroll
        for (int p = 0; p < NP; ++p) {
            float s = sim[b * NP + p];
#pragma unroll
            for (int j = 0; j < 8; ++j) g[j] += s * wp[p][j];
        }
        s16x8 v;
#pragma unroll
        for (int j = 0; j < 8; ++j) v[j] = (short)bf16rtn(g[j]);
        *(s16x8*)(Weff + (size_t)b * ND * ND + off) = v;
    }
}

// ---------------- edge kernel ---------------------------------------------
// block = 256 thr = 4 waves; wave w owns cols [64w, 64w+64) with W_edge
// fragments persistent in registers (128 VGPR). Block processes 2 tiles of
// 64 edges: stage A (f32->bf16) in swizzled LDS, MFMA 4 rowgroups x 4 cg,
// fused ELU+dot epilogue -> one scalar atomicAdd per edge per wave.
__global__ __launch_bounds__(256) void k_edges(
    const float* __restrict__ instr, const float* __restrict__ dist,
    const float* __restrict__ eattrs, const unsigned short* __restrict__ Wbf,
    const float* __restrict__ wrs, const int* __restrict__ ebidx,
    const int* __restrict__ eidx, float* __restrict__ rel_logits)
{
    extern __shared__ char lds[];
    char* Al = lds;                          // 32768 B
    int* ebs = (int*)(lds + 32768);          // 64
    int* dsts = ebs + 64;                    // 64
    float* dscs = (float*)(dsts + 64);       // 64

    int tid = threadIdx.x;
    int lane = tid & 63;
    int wave = tid >> 6;
    int l15 = lane & 15;
    int kg = 8 * (lane >> 4);
    int col0 = wave * 64;

    // persistent B fragments: this wave's 64-col slice of W_edge
    s16x8 bfrag[4][8];
#pragma unroll
    for (int cg = 0; cg < 4; ++cg)
#pragma unroll
        for (int kk = 0; kk < 8; ++kk)
            bfrag[cg][kk] = *(const s16x8*)(Wbf + (size_t)(col0 + cg * 16 + l15) * ND + kk * 32 + kg);

    float wv[4];
#pragma unroll
    for (int cg = 0; cg < 4; ++cg) wv[cg] = wrs[col0 + cg * 16 + l15];

    for (int t = 0; t < 2; ++t) {
        int e0 = (blockIdx.x * 2 + t) * 64;
        if (e0 >= NE) break;
        if (t) __syncthreads();   // previous tile fully consumed

        if (tid < 64) {
            int e = e0 + tid;
            if (e < NE) {
                ebs[tid] = ebidx[e];
                dsts[tid] = eidx[NE + e];
                dscs[tid] = dist[eidx[e]];
            } else { ebs[tid] = 0; dsts[tid] = 0; dscs[tid] = 0.f; }
        }
        // stage A tile (64 edges x 256 k, f32 -> bf16, swizzled)
        {
            int r = tid >> 2;
            int k0 = (tid & 3) * 64;
            int e = e0 + r;
            bool valid = e < NE;
            const float* abase = eattrs + (size_t)e * ND + k0;
#pragma unroll
            for (int j = 0; j < 8; ++j) {
                f32x4 a0 = {0.f, 0.f, 0.f, 0.f}, a1 = {0.f, 0.f, 0.f, 0.f};
                if (valid) {
                    a0 = *(const f32x4*)(abase + j * 8);
                    a1 = *(const f32x4*)(abase + j * 8 + 4);
                }
                *(s16x8*)(Al + swz(r, (k0 + j * 8) * 2)) = pack8(a0, a1);
            }
        }
        __syncthreads();

        f32x4 acc[4][4] = {};
#pragma unroll
        for (int rg = 0; rg < 4; ++rg) {
            int arow = rg * 16 + l15;
#pragma unroll
            for (int kk = 0; kk < 8; ++kk) {
                s16x8 a = *(const s16x8*)(Al + swz(arow, (kk * 32 + kg) * 2));
#pragma unroll
                for (int cg = 0; cg < 4; ++cg)
                    acc[rg][cg] = __builtin_amdgcn_mfma_f32_16x16x32_bf16(a, bfrag[cg][kk], acc[rg][cg], 0, 0, 0);
            }
        }

        // epilogue: partial logit over this wave's 64 cols, per edge
#pragma unroll
        for (int rg = 0; rg < 4; ++rg)
#pragma unroll
            for (int reg = 0; reg < 4; ++reg) {
                int rl = rg * 16 + 4 * (lane >> 4) + reg;
                const float* irow = instr + (size_t)ebs[rl] * ND;
                float p = 0.f;
#pragma unroll
                for (int cg = 0; cg < 4; ++cg) {
                    float x = irow[col0 + cg * 16 + l15] * acc[rg][cg][reg];
                    p += wv[cg] * eluf(x);
                }
                p += __shfl_xor(p, 1, 64);
                p += __shfl_xor(p, 2, 64);
                p += __shfl_xor(p, 4, 64);
                p += __shfl_xor(p, 8, 64);
                if (l15 == 0 && e0 + rl < NE)
                    atomicAdd(&rel_logits[dsts[rl]], dscs[rl] * p);
            }
    }
}

// ---------------- node kernel ---------------------------------------------
// block = (graph b, tile-stride q); wave w owns cols [64w,64w+64) with
// W_eff[b] fragments persistent in registers. Iterates the graph's 64-node
// tiles with stride KQ.
__global__ __launch_bounds__(256) void k_nodes(
    const float* __restrict__ instr, const unsigned short* __restrict__ Weff,
    const float* __restrict__ attrs, const float* __restrict__ wns,
    const int* __restrict__ starts, float* __restrict__ state_logits)
{
    extern __shared__ char lds[];
    char* Al = lds;   // 32768 B

    int b = blockIdx.x & 127;
    int q = blockIdx.x >> 7;
    int s0 = starts[b], s1 = starts[b + 1];
    int nt = (s1 - s0 + 63) >> 6;
    if (q >= nt) return;

    int tid = threadIdx.x;
    int lane = tid & 63;
    int wave = tid >> 6;
    int l15 = lane & 15;
    int kg = 8 * (lane >> 4);
    int col0 = wave * 64;

    const unsigned short* Wb = Weff + (size_t)b * ND * ND;
    s16x8 bfrag[4][8];
#pragma unroll
    for (int cg = 0; cg < 4; ++cg)
#pragma unroll
        for (int kk = 0; kk < 8; ++kk)
            bfrag[cg][kk] = *(const s16x8*)(Wb + (size_t)(col0 + cg * 16 + l15) * ND + kk * 32 + kg);

    float iv[4], wv[4];
#pragma unroll
    for (int cg = 0; cg < 4; ++cg) {
        int col = col0 + cg * 16 + l15;
        iv[cg] = instr[b * ND + col];
        wv[cg] = wns[col];
    }

    for (int ti = q; ti < nt; ti += KQ) {
        int node0 = s0 + ti * 64;
        if (ti != q) __syncthreads();
        // stage A tile (nodes, f32 -> bf16)
        {
            int r = tid >> 2;
            int k0 = (tid & 3) * 64;
            int node = node0 + r;
            bool valid = node < s1;
            const float* abase = attrs + (size_t)node * ND + k0;
#pragma unroll
            for (int j = 0; j < 8; ++j) {
                f32x4 a0 = {0.f, 0.f, 0.f, 0.f}, a1 = {0.f, 0.f, 0.f, 0.f};
                if (valid) {
                    a0 = *(const f32x4*)(abase + j * 8);
                    a1 = *(const f32x4*)(abase + j * 8 + 4);
                }
                *(s16x8*)(Al + swz(r, (k0 + j * 8) * 2)) = pack8(a0, a1);
            }
        }
        __syncthreads();

        f32x4 acc[4][4] = {};
#pragma unroll
        for (int rg = 0; rg < 4; ++rg) {
            int arow = rg * 16 + l15;
#pragma unroll
            for (int kk = 0; kk < 8; ++kk) {
                s16x8 a = *(const s16x8*)(Al + swz(arow, (kk * 32 + kg) * 2));
#pragma unroll
                for (int cg = 0; cg < 4; ++cg)
                    acc[rg][cg] = __builtin_amdgcn_mfma_f32_16x16x32_bf16(a, bfrag[cg][kk], acc[rg][cg], 0, 0, 0);
            }
        }

#pragma unroll
        for (int rg = 0; rg < 4; ++rg)
#pragma unroll
            for (int reg = 0; reg < 4; ++reg) {
                int rl = rg * 16 + 4 * (lane >> 4) + reg;
                float p = 0.f;
#pragma unroll
                for (int cg = 0; cg < 4; ++cg) {
                    float x = iv[cg] * acc[rg][cg][reg];
                    p += wv[cg] * eluf(x);
                }
                p += __shfl_xor(p, 1, 64);
                p += __shfl_xor(p, 2, 64);
                p += __shfl_xor(p, 4, 64);
                p += __shfl_xor(p, 8, 64);
                int node = node0 + rl;
                if (l15 == 0 && node < s1)
                    atomicAdd(&state_logits[node], p);
            }
    }
}

// ---------------- per-graph softmaxes + final mix -------------------------
__global__ __launch_bounds__(256) void k_softmax_mix(
    const float* __restrict__ state_l, const float* __restrict__ rel_l,
    const int* __restrict__ starts, const float* __restrict__ relsim,
    float* __restrict__ out)
{
    __shared__ float wms[4], wmr[4], wss[4], wsr[4];
    int b = blockIdx.x;
    int s0 = starts[b], s1 = starts[b + 1];
    if (s1 <= s0) return;
    int tid = threadIdx.x, lane = tid & 63, wave = tid >> 6;

    float ms = -3.4e38f, mr = -3.4e38f;
    for (int n = s0 + tid; n < s1; n += 256) {
        ms = fmaxf(ms, state_l[n]);
        mr = fmaxf(mr, rel_l[n]);
    }
#pragma unroll
    for (int m = 1; m < 64; m <<= 1) {
        ms = fmaxf(ms, __shfl_xor(ms, m, 64));
        mr = fmaxf(mr, __shfl_xor(mr, m, 64));
    }
    if (lane == 0) { wms[wave] = ms; wmr[wave] = mr; }
    __syncthreads();
    ms = fmaxf(fmaxf(wms[0], wms[1]), fmaxf(wms[2], wms[3]));
    mr = fmaxf(fmaxf(wmr[0], wmr[1]), fmaxf(wmr[2], wmr[3]));

    float ss = 0.f, sr = 0.f;
    for (int n = s0 + tid; n < s1; n += 256) {
        ss += __expf(state_l[n] - ms);
        sr += __expf(rel_l[n] - mr);
    }
#pragma unroll
    for (int m = 1; m < 64; m <<= 1) {
        ss += __shfl_xor(ss, m, 64);
        sr += __shfl_xor(sr, m, 64);
    }
    if (lane == 0) { wss[wave] = ss; wsr[wave] = sr; }
    __syncthreads();
    ss = wss[0] + wss[1] + wss[2] + wss[3];
    sr = wsr[0] + wsr[1] + wsr[2] + wsr[3];

    float rb = relsim[b];
    float iss = 1.f / ss, isr = 1.f / sr;
    for (int n = s0 + tid; n < s1; n += 256) {
        out[n] = rb * __expf(rel_l[n] - mr) * isr
               + (1.f - rb) * __expf(state_l[n] - ms) * iss;
    }
}

extern "C" void kernel_launch(void* const* d_in, const int* in_sizes, int n_in,
                              void* d_out, int out_size, void* d_ws, size_t ws_size,
                              hipStream_t stream) {
    const float* instr  = (const float*)d_in[0];
    const float* dist   = (const float*)d_in[1];
    const float* sim    = (const float*)d_in[2];
    const float* relsim = (const float*)d_in[3];
    const float* nattr  = (const float*)d_in[4];
    const float* eattr  = (const float*)d_in[5];
    const float* Wp     = (const float*)d_in[6];
    const float* We     = (const float*)d_in[7];
    const float* wns    = (const float*)d_in[8];
    const float* wrs    = (const float*)d_in[9];
    const int* nidx     = (const int*)d_in[10];
    const int* ebidx    = (const int*)d_in[11];
    const int* eidx     = (const int*)d_in[12];
    float* out = (float*)d_out;

    char* ws = (char*)d_ws;
    float* rel_logits   = (float*)ws;                      // NN f @ 0
    float* state_logits = rel_logits + NN;                 // NN f @ 200000
    int* starts         = (int*)(ws + 400000);             // B+1 ints
    unsigned short* Wbf = (unsigned short*)(ws + 400640);  // 256*256 bf16
    unsigned short* Weff= (unsigned short*)(ws + 532480);  // 128*256*256 bf16 (16MB)

    hipMemsetAsync(rel_logits, 0, 2 * NN * sizeof(float), stream);
    k_wedge_bf16<<<64, 256, 0, stream>>>(We, Wbf);
    k_weff<<<dim3(32, 8), 256, 0, stream>>>(sim, Wp, Weff);
    k_starts<<<(NN + 255) / 256, 256, 0, stream>>>(nidx, starts);
    k_edges<<<(NE + 127) / 128, 256, 33536, stream>>>(instr, dist, eattr, Wbf, wrs,
                                                      ebidx, eidx, rel_logits);
    k_nodes<<<NB * KQ, 256, 32768, stream>>>(instr, Weff, nattr, wns, starts,
                                             state_logits);
    k_softmax_mix<<<NB, 256, 0, stream>>>(state_logits, rel_logits, starts,
                                          relsim, out);
}

// Round 3
// 296.836 us; speedup vs baseline: 1.5470x; 1.3038x over previous
//
#include <hip/hip_runtime.h>

#define NB 128
#define NN 50000
#define NE 300000
#define ND 256
#define NP 8

typedef __attribute__((ext_vector_type(4))) float f32x4;
typedef __attribute__((ext_vector_type(8))) short s16x8;

__device__ __forceinline__ unsigned short bf16rtn(float f) {
    unsigned int u = __float_as_uint(f);
    unsigned int r = (u + 0x7fffu + ((u >> 16) & 1u)) >> 16;
    return (unsigned short)r;
}

// swizzled LDS byte offset for [row][256 bf16] tiles (row stride 512B),
// XOR bits 4-6 with row&7 -> conflict-free ds_read_b128 (guide G4 pattern)
__device__ __forceinline__ int swz(int row, int kbyte) {
    return row * 512 + (kbyte ^ ((row & 7) << 4));
}

__device__ __forceinline__ s16x8 pack8(f32x4 a, f32x4 b) {
    s16x8 v;
    v[0] = (short)bf16rtn(a[0]); v[1] = (short)bf16rtn(a[1]);
    v[2] = (short)bf16rtn(a[2]); v[3] = (short)bf16rtn(a[3]);
    v[4] = (short)bf16rtn(b[0]); v[5] = (short)bf16rtn(b[1]);
    v[6] = (short)bf16rtn(b[2]); v[7] = (short)bf16rtn(b[3]);
    return v;
}

__device__ __forceinline__ float eluf(float x) {
    return x > 0.f ? x : __expf(x) - 1.f;
}

// ---------------- segment boundary kernel (node_indices is sorted) ---------
__global__ void k_starts(const int* __restrict__ idx, int* __restrict__ starts) {
    int n = blockIdx.x * blockDim.x + threadIdx.x;
    if (n >= NN) return;
    int cur = idx[n];
    int prev = (n == 0) ? -1 : idx[n - 1];
    for (int b2 = prev + 1; b2 <= cur; ++b2) starts[b2] = n;
    if (n == NN - 1)
        for (int b2 = cur + 1; b2 <= NB; ++b2) starts[b2] = NN;
}

// ---------------- W_edge f32 -> bf16 --------------------------------------
__global__ void k_wedge_bf16(const float* __restrict__ w, unsigned short* __restrict__ o) {
    int i = (blockIdx.x * 256 + threadIdx.x) * 4;
    f32x4 v = *(const f32x4*)(w + i);
    o[i + 0] = bf16rtn(v[0]); o[i + 1] = bf16rtn(v[1]);
    o[i + 2] = bf16rtn(v[2]); o[i + 3] = bf16rtn(v[3]);
}

// ---------------- W_eff[b] = sum_p sim[b,p] * W_p  (f32 -> bf16) ----------
__global__ __launch_bounds__(256) void k_weff(
    const float* __restrict__ sim, const float* __restrict__ Wp,
    unsigned short* __restrict__ Weff)
{
    int chunk = blockIdx.x * 256 + threadIdx.x;   // 0..8191, 8 elems each
    int off = chunk * 8;
    float wp[NP][8];
#pragma unroll
    for (int p = 0; p < NP; ++p) {
        const float* src = Wp + (size_t)p * ND * ND + off;
        f32x4 w0 = *(const f32x4*)src;
        f32x4 w1 = *(const f32x4*)(src + 4);
        wp[p][0] = w0[0]; wp[p][1] = w0[1]; wp[p][2] = w0[2]; wp[p][3] = w0[3];
        wp[p][4] = w1[0]; wp[p][5] = w1[1]; wp[p][6] = w1[2]; wp[p][7] = w1[3];
    }
    int b0 = blockIdx.y * 16;
    for (int bb = 0; bb < 16; ++bb) {
        int b = b0 + bb;
        float g[8] = {0.f, 0.f, 0.f, 0.f, 0.f, 0.f, 0.f, 0.f};
#pragma unroll
        for (int p = 0; p < NP; ++p) {
            float s = sim[b * NP + p];
#pragma unroll
            for (int j = 0; j < 8; ++j) g[j] += s * wp[p][j];
        }
        s16x8 v;
#pragma unroll
        for (int j = 0; j < 8; ++j) v[j] = (short)bf16rtn(g[j]);
        *(s16x8*)(Weff + (size_t)b * ND * ND + off) = v;
    }
}

// ---------------- edge kernel ---------------------------------------------
// 1024 thr = 16 waves; wave w owns 16 cols of W_edge (bfrag = 32 VGPR,
// acc = 16 VGPR -> <=128 regs, full block resident = 4 waves/SIMD).
// One 64-edge tile per block. Coalesced stage (wave reads 4 consecutive
// 1KB rows). Cross-wave combine via LDS part[16][64] -> 1 atomic per edge.
__global__ __launch_bounds__(1024) void k_edges(
    const float* __restrict__ instr, const float* __restrict__ dist,
    const float* __restrict__ eattrs, const unsigned short* __restrict__ Wbf,
    const float* __restrict__ wrs, const int* __restrict__ ebidx,
    const int* __restrict__ eidx, float* __restrict__ rel_logits)
{
    __shared__ char Al[32768];
    __shared__ int ebs[64];
    __shared__ int dsts[64];
    __shared__ float dscs[64];
    __shared__ float part[16][64];

    int tid = threadIdx.x;
    int lane = tid & 63;
    int wave = tid >> 6;        // 0..15
    int l15 = lane & 15;
    int q = lane >> 4;          // 0..3
    int col0 = wave * 16;
    int e0 = blockIdx.x * 64;

    if (tid < 64) {
        int e = e0 + tid;
        if (e < NE) {
            ebs[tid] = ebidx[e];
            dsts[tid] = eidx[NE + e];
            dscs[tid] = dist[eidx[e]];
        } else { ebs[tid] = 0; dsts[tid] = 0; dscs[tid] = 0.f; }
    }

    // persistent B fragments: this wave's 16-col slice of W_edge
    s16x8 bfrag[8];
#pragma unroll
    for (int kk = 0; kk < 8; ++kk)
        bfrag[kk] = *(const s16x8*)(Wbf + (size_t)(col0 + l15) * ND + kk * 32 + q * 8);
    float wv = wrs[col0 + l15];

    // ---- stage A tile: thread -> row tid>>4, 16 floats at (tid&15)*16 ----
    {
        int r = tid >> 4;
        int f0 = (tid & 15) * 16;
        int e = e0 + r;
        const float* abase = eattrs + (size_t)e * ND + f0;
        f32x4 a0 = {0,0,0,0}, a1 = {0,0,0,0}, a2 = {0,0,0,0}, a3 = {0,0,0,0};
        if (e < NE) {
            a0 = *(const f32x4*)(abase);
            a1 = *(const f32x4*)(abase + 4);
            a2 = *(const f32x4*)(abase + 8);
            a3 = *(const f32x4*)(abase + 12);
        }
        *(s16x8*)(Al + swz(r, f0 * 2)) = pack8(a0, a1);
        *(s16x8*)(Al + swz(r, f0 * 2 + 16)) = pack8(a2, a3);
    }
    __syncthreads();

    // ---- MFMA: 4 rowgroups x 8 k-steps, 16 cols ----
    f32x4 acc[4] = {};
#pragma unroll
    for (int rg = 0; rg < 4; ++rg) {
        int arow = rg * 16 + l15;
#pragma unroll
        for (int kk = 0; kk < 8; ++kk) {
            s16x8 a = *(const s16x8*)(Al + swz(arow, kk * 64 + q * 16));
            acc[rg] = __builtin_amdgcn_mfma_f32_16x16x32_bf16(a, bfrag[kk], acc[rg], 0, 0, 0);
        }
    }

    // ---- epilogue: 16-col partial logit per edge -> LDS ----
#pragma unroll
    for (int rg = 0; rg < 4; ++rg)
#pragma unroll
        for (int reg = 0; reg < 4; ++reg) {
            int rl = rg * 16 + 4 * q + reg;
            const float* irow = instr + (size_t)ebs[rl] * ND;
            float x = irow[col0 + l15] * acc[rg][reg];
            float p = wv * eluf(x);
            p += __shfl_xor(p, 1, 64);
            p += __shfl_xor(p, 2, 64);
            p += __shfl_xor(p, 4, 64);
            p += __shfl_xor(p, 8, 64);
            if (l15 == 0) part[wave][rl] = p;
        }
    __syncthreads();

    if (tid < 64 && e0 + tid < NE) {
        float s = 0.f;
#pragma unroll
        for (int w = 0; w < 16; ++w) s += part[w][tid];
        atomicAdd(&rel_logits[dsts[tid]], dscs[tid] * s);
    }
}

// ---------------- node kernel ---------------------------------------------
// Same structure; block covers all 256 cols of one graph tile -> plain store.
// grid = NB*2: (b = idx>>1, strided tiles q = idx&1, step 2).
__global__ __launch_bounds__(1024) void k_nodes(
    const float* __restrict__ instr, const unsigned short* __restrict__ Weff,
    const float* __restrict__ attrs, const float* __restrict__ wns,
    const int* __restrict__ starts, float* __restrict__ state_logits)
{
    __shared__ char Al[32768];
    __shared__ float part[16][64];

    int b = blockIdx.x >> 1;
    int qb = blockIdx.x & 1;
    int s0 = starts[b], s1 = starts[b + 1];
    int nt = (s1 - s0 + 63) >> 6;
    if (qb >= nt) return;

    int tid = threadIdx.x;
    int lane = tid & 63;
    int wave = tid >> 6;
    int l15 = lane & 15;
    int q = lane >> 4;
    int col0 = wave * 16;

    const unsigned short* Wb = Weff + (size_t)b * ND * ND;
    s16x8 bfrag[8];
#pragma unroll
    for (int kk = 0; kk < 8; ++kk)
        bfrag[kk] = *(const s16x8*)(Wb + (size_t)(col0 + l15) * ND + kk * 32 + q * 8);
    float iv = instr[b * ND + col0 + l15];
    float wv = wns[col0 + l15];

    for (int ti = qb; ti < nt; ti += 2) {
        int node0 = s0 + ti * 64;
        if (ti != qb) __syncthreads();
        {
            int r = tid >> 4;
            int f0 = (tid & 15) * 16;
            int node = node0 + r;
            const float* abase = attrs + (size_t)node * ND + f0;
            f32x4 a0 = {0,0,0,0}, a1 = {0,0,0,0}, a2 = {0,0,0,0}, a3 = {0,0,0,0};
            if (node < s1) {
                a0 = *(const f32x4*)(abase);
                a1 = *(const f32x4*)(abase + 4);
                a2 = *(const f32x4*)(abase + 8);
                a3 = *(const f32x4*)(abase + 12);
            }
            *(s16x8*)(Al + swz(r, f0 * 2)) = pack8(a0, a1);
            *(s16x8*)(Al + swz(r, f0 * 2 + 16)) = pack8(a2, a3);
        }
        __syncthreads();

        f32x4 acc[4] = {};
#pragma unroll
        for (int rg = 0; rg < 4; ++rg) {
            int arow = rg * 16 + l15;
#pragma unroll
            for (int kk = 0; kk < 8; ++kk) {
                s16x8 a = *(const s16x8*)(Al + swz(arow, kk * 64 + q * 16));
                acc[rg] = __builtin_amdgcn_mfma_f32_16x16x32_bf16(a, bfrag[kk], acc[rg], 0, 0, 0);
            }
        }

#pragma unroll
        for (int rg = 0; rg < 4; ++rg)
#pragma unroll
            for (int reg = 0; reg < 4; ++reg) {
                int rl = rg * 16 + 4 * q + reg;
                float p = wv * eluf(iv * acc[rg][reg]);
                p += __shfl_xor(p, 1, 64);
                p += __shfl_xor(p, 2, 64);
                p += __shfl_xor(p, 4, 64);
                p += __shfl_xor(p, 8, 64);
                if (l15 == 0) part[wave][rl] = p;
            }
        __syncthreads();

        if (tid < 64) {
            int node = node0 + tid;
            if (node < s1) {
                float s = 0.f;
#pragma unroll
                for (int w = 0; w < 16; ++w) s += part[w][tid];
                state_logits[node] = s;
            }
        }
    }
}

// ---------------- per-graph softmaxes + final mix -------------------------
__global__ __launch_bounds__(256) void k_softmax_mix(
    const float* __restrict__ state_l, const float* __restrict__ rel_l,
    const int* __restrict__ starts, const float* __restrict__ relsim,
    float* __restrict__ out)
{
    __shared__ float wms[4], wmr[4], wss[4], wsr[4];
    int b = blockIdx.x;
    int s0 = starts[b], s1 = starts[b + 1];
    if (s1 <= s0) return;
    int tid = threadIdx.x, lane = tid & 63, wave = tid >> 6;

    float ms = -3.4e38f, mr = -3.4e38f;
    for (int n = s0 + tid; n < s1; n += 256) {
        ms = fmaxf(ms, state_l[n]);
        mr = fmaxf(mr, rel_l[n]);
    }
#pragma unroll
    for (int m = 1; m < 64; m <<= 1) {
        ms = fmaxf(ms, __shfl_xor(ms, m, 64));
        mr = fmaxf(mr, __shfl_xor(mr, m, 64));
    }
    if (lane == 0) { wms[wave] = ms; wmr[wave] = mr; }
    __syncthreads();
    ms = fmaxf(fmaxf(wms[0], wms[1]), fmaxf(wms[2], wms[3]));
    mr = fmaxf(fmaxf(wmr[0], wmr[1]), fmaxf(wmr[2], wmr[3]));

    float ss = 0.f, sr = 0.f;
    for (int n = s0 + tid; n < s1; n += 256) {
        ss += __expf(state_l[n] - ms);
        sr += __expf(rel_l[n] - mr);
    }
#pragma unroll
    for (int m = 1; m < 64; m <<= 1) {
        ss += __shfl_xor(ss, m, 64);
        sr += __shfl_xor(sr, m, 64);
    }
    if (lane == 0) { wss[wave] = ss; wsr[wave] = sr; }
    __syncthreads();
    ss = wss[0] + wss[1] + wss[2] + wss[3];
    sr = wsr[0] + wsr[1] + wsr[2] + wsr[3];

    float rb = relsim[b];
    float iss = 1.f / ss, isr = 1.f / sr;
    for (int n = s0 + tid; n < s1; n += 256) {
        out[n] = rb * __expf(rel_l[n] - mr) * isr
               + (1.f - rb) * __expf(state_l[n] - ms) * iss;
    }
}

extern "C" void kernel_launch(void* const* d_in, const int* in_sizes, int n_in,
                              void* d_out, int out_size, void* d_ws, size_t ws_size,
                              hipStream_t stream) {
    const float* instr  = (const float*)d_in[0];
    const float* dist   = (const float*)d_in[1];
    const float* sim    = (const float*)d_in[2];
    const float* relsim = (const float*)d_in[3];
    const float* nattr  = (const float*)d_in[4];
    const float* eattr  = (const float*)d_in[5];
    const float* Wp     = (const float*)d_in[6];
    const float* We     = (const float*)d_in[7];
    const float* wns    = (const float*)d_in[8];
    const float* wrs    = (const float*)d_in[9];
    const int* nidx     = (const int*)d_in[10];
    const int* ebidx    = (const int*)d_in[11];
    const int* eidx     = (const int*)d_in[12];
    float* out = (float*)d_out;

    char* ws = (char*)d_ws;
    float* rel_logits   = (float*)ws;                      // NN f @ 0
    float* state_logits = rel_logits + NN;                 // NN f @ 200000
    int* starts         = (int*)(ws + 400000);             // B+1 ints
    unsigned short* Wbf = (unsigned short*)(ws + 400640);  // 256*256 bf16
    unsigned short* Weff= (unsigned short*)(ws + 532480);  // 128*256*256 bf16 (16MB)

    hipMemsetAsync(rel_logits, 0, NN * sizeof(float), stream);
    k_wedge_bf16<<<64, 256, 0, stream>>>(We, Wbf);
    k_weff<<<dim3(32, 8), 256, 0, stream>>>(sim, Wp, Weff);
    k_starts<<<(NN + 255) / 256, 256, 0, stream>>>(nidx, starts);
    k_edges<<<(NE + 63) / 64, 1024, 0, stream>>>(instr, dist, eattr, Wbf, wrs,
                                                 ebidx, eidx, rel_logits);
    k_nodes<<<NB * 2, 1024, 0, stream>>>(instr, Weff, nattr, wns, starts,
                                         state_logits);
    k_softmax_mix<<<NB, 256, 0, stream>>>(state_logits, rel_logits, starts,
                                          relsim, out);
}

// Round 4
// 283.725 us; speedup vs baseline: 1.6185x; 1.0462x over previous
//
#include <hip/hip_runtime.h>

#define NB 128
#define NN 50000
#define NE 300000
#define ND 256
#define NP 8

typedef __attribute__((ext_vector_type(4))) float f32x4;
typedef __attribute__((ext_vector_type(8))) short s16x8;
typedef __attribute__((ext_vector_type(4))) short s16x4;

__device__ __forceinline__ unsigned short bf16rtn(float f) {
    unsigned int u = __float_as_uint(f);
    unsigned int r = (u + 0x7fffu + ((u >> 16) & 1u)) >> 16;
    return (unsigned short)r;
}

// swizzled LDS byte offset for [row][256 bf16] tiles (row stride 512B),
// XOR bits 4-6 with row&7 -> conflict-free ds_read_b128 (guide G4 pattern)
__device__ __forceinline__ int swz(int row, int kbyte) {
    return row * 512 + (kbyte ^ ((row & 7) << 4));
}

__device__ __forceinline__ float eluf(float x) {
    return x > 0.f ? x : __expf(x) - 1.f;
}

// sum across the 16 lanes of a DPP row (VALU-only butterfly, no LDS).
// row_ror:n = dpp_ctrl 0x120|n; after ror 1,2,4,8 every lane holds the row sum.
__device__ __forceinline__ float rowsum16(float x) {
    int t;
    t = __builtin_amdgcn_update_dpp(0, __float_as_int(x), 0x121, 0xf, 0xf, true);
    x += __int_as_float(t);
    t = __builtin_amdgcn_update_dpp(0, __float_as_int(x), 0x122, 0xf, 0xf, true);
    x += __int_as_float(t);
    t = __builtin_amdgcn_update_dpp(0, __float_as_int(x), 0x124, 0xf, 0xf, true);
    x += __int_as_float(t);
    t = __builtin_amdgcn_update_dpp(0, __float_as_int(x), 0x128, 0xf, 0xf, true);
    x += __int_as_float(t);
    return x;
}

// ---------------- segment boundary kernel (node_indices is sorted) ---------
__global__ void k_starts(const int* __restrict__ idx, int* __restrict__ starts) {
    int n = blockIdx.x * blockDim.x + threadIdx.x;
    if (n >= NN) return;
    int cur = idx[n];
    int prev = (n == 0) ? -1 : idx[n - 1];
    for (int b2 = prev + 1; b2 <= cur; ++b2) starts[b2] = n;
    if (n == NN - 1)
        for (int b2 = cur + 1; b2 <= NB; ++b2) starts[b2] = NN;
}

// ---------------- W_edge f32 -> bf16 --------------------------------------
__global__ void k_wedge_bf16(const float* __restrict__ w, unsigned short* __restrict__ o) {
    int i = (blockIdx.x * 256 + threadIdx.x) * 4;
    f32x4 v = *(const f32x4*)(w + i);
    o[i + 0] = bf16rtn(v[0]); o[i + 1] = bf16rtn(v[1]);
    o[i + 2] = bf16rtn(v[2]); o[i + 3] = bf16rtn(v[3]);
}

// ---------------- W_eff[b] = sum_p sim[b,p] * W_p  (f32 -> bf16) ----------
__global__ __launch_bounds__(256) void k_weff(
    const float* __restrict__ sim, const float* __restrict__ Wp,
    unsigned short* __restrict__ Weff)
{
    int chunk = blockIdx.x * 256 + threadIdx.x;
    int off = chunk * 8;
    float wp[NP][8];
#pragma unroll
    for (int p = 0; p < NP; ++p) {
        const float* src = Wp + (size_t)p * ND * ND + off;
        f32x4 w0 = *(const f32x4*)src;
        f32x4 w1 = *(const f32x4*)(src + 4);
        wp[p][0] = w0[0]; wp[p][1] = w0[1]; wp[p][2] = w0[2]; wp[p][3] = w0[3];
        wp[p][4] = w1[0]; wp[p][5] = w1[1]; wp[p][6] = w1[2]; wp[p][7] = w1[3];
    }
    int b0 = blockIdx.y * 16;
    for (int bb = 0; bb < 16; ++bb) {
        int b = b0 + bb;
        float g[8] = {0.f, 0.f, 0.f, 0.f, 0.f, 0.f, 0.f, 0.f};
#pragma unroll
        for (int p = 0; p < NP; ++p) {
            float s = sim[b * NP + p];
#pragma unroll
            for (int j = 0; j < 8; ++j) g[j] += s * wp[p][j];
        }
        s16x8 v;
#pragma unroll
        for (int j = 0; j < 8; ++j) v[j] = (short)bf16rtn(g[j]);
        *(s16x8*)(Weff + (size_t)b * ND * ND + off) = v;
    }
}

// ---- shared staging: 64-row x 256-col f32 tile -> bf16 swizzled LDS ------
// lane layout: row r = tid>>4, lane-col i = tid&15; lane loads 4x16B strided
// (coalesced 256B per 16 lanes) and writes 4x s16x4 (8B) at byte 8i+128j
// -> banks 2i,2i+1: conflict-free.
template <typename GUARD>
__device__ __forceinline__ void stage_tile(char* Al, const float* base_row0,
                                           int tid, GUARD valid_row) {
    int r = tid >> 4;
    int i = tid & 15;
    bool valid = valid_row(r);
    const float* abase = base_row0 + (size_t)r * ND + i * 4;
#pragma unroll
    for (int j = 0; j < 4; ++j) {
        f32x4 a = {0.f, 0.f, 0.f, 0.f};
        if (valid) a = *(const f32x4*)(abase + 64 * j);
        s16x4 v;
        v[0] = (short)bf16rtn(a[0]); v[1] = (short)bf16rtn(a[1]);
        v[2] = (short)bf16rtn(a[2]); v[3] = (short)bf16rtn(a[3]);
        *(s16x4*)(Al + r * 512 + (((i << 3) + (j << 7)) ^ ((r & 7) << 4))) = v;
    }
}

// ---------------- edge kernel ---------------------------------------------
// 1024 thr = 16 waves = 2 rowquads (32 edges) x 8 colquads (32 cols).
// Per wave: 2rg x 2cg, bfrag 64 VGPR, acc 16 VGPR. One 64-edge tile/block.
// Epilogue: DPP rowsum -> part[8][64] -> 1 atomic per edge.
__global__ __launch_bounds__(1024) void k_edges(
    const float* __restrict__ instr, const float* __restrict__ dist,
    const float* __restrict__ eattrs, const unsigned short* __restrict__ Wbf,
    const float* __restrict__ wrs, const int* __restrict__ ebidx,
    const int* __restrict__ eidx, float* __restrict__ rel_logits)
{
    __shared__ char Al[32768];
    __shared__ float part[8][64];
    __shared__ int ebs[64];
    __shared__ int dsts[64];
    __shared__ float dscs[64];

    int tid = threadIdx.x;
    int lane = tid & 63;
    int wave = tid >> 6;        // 0..15
    int l15 = lane & 15;
    int q = lane >> 4;          // 0..3
    int rq = wave >> 3;         // 0..1 (rows rq*32..rq*32+31)
    int cq = wave & 7;          // 0..7 (cols cq*32..cq*32+31)
    int e0 = blockIdx.x * 64;

    if (tid < 64) {
        int e = e0 + tid;
        if (e < NE) {
            ebs[tid] = ebidx[e];
            dsts[tid] = eidx[NE + e];
            dscs[tid] = dist[eidx[e]];
        } else { ebs[tid] = 0; dsts[tid] = 0; dscs[tid] = 0.f; }
    }

    // persistent B fragments: this wave's 2x16-col slice of W_edge
    s16x8 bfrag[2][8];
#pragma unroll
    for (int cg = 0; cg < 2; ++cg)
#pragma unroll
        for (int kk = 0; kk < 8; ++kk)
            bfrag[cg][kk] = *(const s16x8*)(Wbf + (size_t)(cq * 32 + cg * 16 + l15) * ND + kk * 32 + q * 8);
    float wv0 = wrs[cq * 32 + l15];
    float wv1 = wrs[cq * 32 + 16 + l15];

    stage_tile(Al, eattrs + (size_t)e0 * ND, tid,
               [&](int r) { return e0 + r < NE; });
    __syncthreads();

    f32x4 acc[2][2] = {};
#pragma unroll
    for (int rg = 0; rg < 2; ++rg) {
        int arow = rq * 32 + rg * 16 + l15;
#pragma unroll
        for (int kk = 0; kk < 8; ++kk) {
            s16x8 a = *(const s16x8*)(Al + swz(arow, kk * 64 + q * 16));
            acc[rg][0] = __builtin_amdgcn_mfma_f32_16x16x32_bf16(a, bfrag[0][kk], acc[rg][0], 0, 0, 0);
            acc[rg][1] = __builtin_amdgcn_mfma_f32_16x16x32_bf16(a, bfrag[1][kk], acc[rg][1], 0, 0, 0);
        }
    }

    // epilogue: 32-col partial logit per edge via DPP rowsum
#pragma unroll
    for (int rg = 0; rg < 2; ++rg)
#pragma unroll
        for (int reg = 0; reg < 4; ++reg) {
            int rl = rq * 32 + rg * 16 + 4 * q + reg;
            const float* irow = instr + (size_t)ebs[rl] * ND;
            float x0 = irow[cq * 32 + l15] * acc[rg][0][reg];
            float x1 = irow[cq * 32 + 16 + l15] * acc[rg][1][reg];
            float p = rowsum16(wv0 * eluf(x0) + wv1 * eluf(x1));
            if (l15 == 0) part[cq][rl] = p;
        }
    __syncthreads();

    if (tid < 64 && e0 + tid < NE) {
        float s = 0.f;
#pragma unroll
        for (int w = 0; w < 8; ++w) s += part[w][tid];
        atomicAdd(&rel_logits[dsts[tid]], dscs[tid] * s);
    }
}

// ---------------- node kernel ---------------------------------------------
// Same template; full 256 cols per block -> plain store of state logits.
__global__ __launch_bounds__(1024) void k_nodes(
    const float* __restrict__ instr, const unsigned short* __restrict__ Weff,
    const float* __restrict__ attrs, const float* __restrict__ wns,
    const int* __restrict__ starts, float* __restrict__ state_logits)
{
    __shared__ char Al[32768];
    __shared__ float part[8][64];

    int b = blockIdx.x >> 1;
    int qb = blockIdx.x & 1;
    int s0 = starts[b], s1 = starts[b + 1];
    int nt = (s1 - s0 + 63) >> 6;
    if (qb >= nt) return;

    int tid = threadIdx.x;
    int lane = tid & 63;
    int wave = tid >> 6;
    int l15 = lane & 15;
    int q = lane >> 4;
    int rq = wave >> 3;
    int cq = wave & 7;

    const unsigned short* Wb = Weff + (size_t)b * ND * ND;
    s16x8 bfrag[2][8];
#pragma unroll
    for (int cg = 0; cg < 2; ++cg)
#pragma unroll
        for (int kk = 0; kk < 8; ++kk)
            bfrag[cg][kk] = *(const s16x8*)(Wb + (size_t)(cq * 32 + cg * 16 + l15) * ND + kk * 32 + q * 8);
    float iv0 = instr[b * ND + cq * 32 + l15];
    float iv1 = instr[b * ND + cq * 32 + 16 + l15];
    float wv0 = wns[cq * 32 + l15];
    float wv1 = wns[cq * 32 + 16 + l15];

    for (int ti = qb; ti < nt; ti += 2) {
        int node0 = s0 + ti * 64;
        if (ti != qb) __syncthreads();
        stage_tile(Al, attrs + (size_t)node0 * ND, tid,
                   [&](int r) { return node0 + r < s1; });
        __syncthreads();

        f32x4 acc[2][2] = {};
#pragma unroll
        for (int rg = 0; rg < 2; ++rg) {
            int arow = rq * 32 + rg * 16 + l15;
#pragma unroll
            for (int kk = 0; kk < 8; ++kk) {
                s16x8 a = *(const s16x8*)(Al + swz(arow, kk * 64 + q * 16));
                acc[rg][0] = __builtin_amdgcn_mfma_f32_16x16x32_bf16(a, bfrag[0][kk], acc[rg][0], 0, 0, 0);
                acc[rg][1] = __builtin_amdgcn_mfma_f32_16x16x32_bf16(a, bfrag[1][kk], acc[rg][1], 0, 0, 0);
            }
        }

#pragma unroll
        for (int rg = 0; rg < 2; ++rg)
#pragma unroll
            for (int reg = 0; reg < 4; ++reg) {
                int rl = rq * 32 + rg * 16 + 4 * q + reg;
                float p = rowsum16(wv0 * eluf(iv0 * acc[rg][0][reg])
                                 + wv1 * eluf(iv1 * acc[rg][1][reg]));
                if (l15 == 0) part[cq][rl] = p;
            }
        __syncthreads();

        if (tid < 64) {
            int node = node0 + tid;
            if (node < s1) {
                float s = 0.f;
#pragma unroll
                for (int w = 0; w < 8; ++w) s += part[w][tid];
                state_logits[node] = s;
            }
        }
    }
}

// ---------------- per-graph softmaxes + final mix -------------------------
__global__ __launch_bounds__(256) void k_softmax_mix(
    const float* __restrict__ state_l, const float* __restrict__ rel_l,
    const int* __restrict__ starts, const float* __restrict__ relsim,
    float* __restrict__ out)
{
    __shared__ float wms[4], wmr[4], wss[4], wsr[4];
    int b = blockIdx.x;
    int s0 = starts[b], s1 = starts[b + 1];
    if (s1 <= s0) return;
    int tid = threadIdx.x, lane = tid & 63, wave = tid >> 6;

    float ms = -3.4e38f, mr = -3.4e38f;
    for (int n = s0 + tid; n < s1; n += 256) {
        ms = fmaxf(ms, state_l[n]);
        mr = fmaxf(mr, rel_l[n]);
    }
#pragma unroll
    for (int m = 1; m < 64; m <<= 1) {
        ms = fmaxf(ms, __shfl_xor(ms, m, 64));
        mr = fmaxf(mr, __shfl_xor(mr, m, 64));
    }
    if (lane == 0) { wms[wave] = ms; wmr[wave] = mr; }
    __syncthreads();
    ms = fmaxf(fmaxf(wms[0], wms[1]), fmaxf(wms[2], wms[3]));
    mr = fmaxf(fmaxf(wmr[0], wmr[1]), fmaxf(wmr[2], wmr[3]));

    float ss = 0.f, sr = 0.f;
    for (int n = s0 + tid; n < s1; n += 256) {
        ss += __expf(state_l[n] - ms);
        sr += __expf(rel_l[n] - mr);
    }
#pragma unroll
    for (int m = 1; m < 64; m <<= 1) {
        ss += __shfl_xor(ss, m, 64);
        sr += __shfl_xor(sr, m, 64);
    }
    if (lane == 0) { wss[wave] = ss; wsr[wave] = sr; }
    __syncthreads();
    ss = wss[0] + wss[1] + wss[2] + wss[3];
    sr = wsr[0] + wsr[1] + wsr[2] + wsr[3];

    float rb = relsim[b];
    float iss = 1.f / ss, isr = 1.f / sr;
    for (int n = s0 + tid; n < s1; n += 256) {
        out[n] = rb * __expf(rel_l[n] - mr) * isr
               + (1.f - rb) * __expf(state_l[n] - ms) * iss;
    }
}

extern "C" void kernel_launch(void* const* d_in, const int* in_sizes, int n_in,
                              void* d_out, int out_size, void* d_ws, size_t ws_size,
                              hipStream_t stream) {
    const float* instr  = (const float*)d_in[0];
    const float* dist   = (const float*)d_in[1];
    const float* sim    = (const float*)d_in[2];
    const float* relsim = (const float*)d_in[3];
    const float* nattr  = (const float*)d_in[4];
    const float* eattr  = (const float*)d_in[5];
    const float* Wp     = (const float*)d_in[6];
    const float* We     = (const float*)d_in[7];
    const float* wns    = (const float*)d_in[8];
    const float* wrs    = (const float*)d_in[9];
    const int* nidx     = (const int*)d_in[10];
    const int* ebidx    = (const int*)d_in[11];
    const int* eidx     = (const int*)d_in[12];
    float* out = (float*)d_out;

    char* ws = (char*)d_ws;
    float* rel_logits   = (float*)ws;                      // NN f @ 0
    float* state_logits = rel_logits + NN;                 // NN f @ 200000
    int* starts         = (int*)(ws + 400000);             // B+1 ints
    unsigned short* Wbf = (unsigned short*)(ws + 400640);  // 256*256 bf16
    unsigned short* Weff= (unsigned short*)(ws + 532480);  // 128*256*256 bf16 (16MB)

    hipMemsetAsync(rel_logits, 0, NN * sizeof(float), stream);
    k_wedge_bf16<<<64, 256, 0, stream>>>(We, Wbf);
    k_weff<<<dim3(32, 8), 256, 0, stream>>>(sim, Wp, Weff);
    k_starts<<<(NN + 255) / 256, 256, 0, stream>>>(nidx, starts);
    k_edges<<<(NE + 63) / 64, 1024, 0, stream>>>(instr, dist, eattr, Wbf, wrs,
                                                 ebidx, eidx, rel_logits);
    k_nodes<<<NB * 2, 1024, 0, stream>>>(instr, Weff, nattr, wns, starts,
                                         state_logits);
    k_softmax_mix<<<NB, 256, 0, stream>>>(state_logits, rel_logits, starts,
                                          relsim, out);
}